// Round 9
// baseline (81.053 us; speedup 1.0000x reference)
//
#include <hip/hip_runtime.h>
#include <cfloat>

#define SCOPE 5
#define MASK_MAG 9999.0f
constexpr int F = 256;     // hiddenNoduleNumbers
constexpr int TW = 32;     // t's per wave
constexpr int WAVES = 4;   // waves per block

// DPP-based partial reduction: quad + row sums (VALU, 1 op each), then 2 shfl.
template <int CTRL>
__device__ __forceinline__ float dppadd(float x) {
    int v = __builtin_amdgcn_update_dpp(0, __float_as_int(x), CTRL, 0xF, 0xF, true);
    return x + __int_as_float(v);
}
__device__ __forceinline__ float wave_sum(float s) {
    s = dppadd<0xB1>(s);   // + lane^1 (quad_perm 1,0,3,2)
    s = dppadd<0x4E>(s);   // + lane^2 (quad_perm 2,3,0,1)
    s = dppadd<0x141>(s);  // + lane^4 (row_half_mirror)
    s = dppadd<0x140>(s);  // + lane^8 (row_mirror) -> 16-lane sums
    s += __shfl_xor(s, 16, 64);
    s += __shfl_xor(s, 32, 64);
    return s;
}

// ---------------------------------------------------------------------------
// K1: fused sliding-window scores + online-softmax weighted accumulation.
// (identical to R7 — kept as the measured baseline structure)
// ---------------------------------------------------------------------------
__global__ __launch_bounds__(256) void fused_kernel(
    const float* __restrict__ data, const float* __restrict__ W,
    const float* __restrict__ bias, const int* __restrict__ seq,
    float* __restrict__ scores, float* __restrict__ pacc,
    float* __restrict__ pm, float* __restrict__ ps, int T) {
    const int b = blockIdx.y;
    const int tid = threadIdx.x;
    const int lane = tid & 63;
    const int wid = tid >> 6;
    const int lane4 = lane * 4;
    const int widx = blockIdx.x * WAVES + wid;
    const int t0 = widx * TW;
    const int npw = T / TW;
    const float* __restrict__ dBase = data + (size_t)b * T * F;
    float* __restrict__ sb = scores + (size_t)b * T;
    const float bv = bias[0];
    const int L = seq[b];

    float4 w[SCOPE];
    #pragma unroll
    for (int v = 0; v < SCOPE; ++v)
        w[v] = *(const float4*)(W + v * F + lane4);

    const float4 fz = make_float4(0.f, 0.f, 0.f, 0.f);
    float4 S[24];

#define SLOT(r) ((r) % 24)
#define LOADROW(slot, off) do { \
    const int uu = t0 + (off); \
    S[slot] = (uu < T) ? *(const float4*)(dBase + (size_t)uu * F + lane4) : fz; \
    } while (0)
#define DOT4(a, b) ((a).x*(b).x + (a).y*(b).y + (a).z*(b).z + (a).w*(b).w)

    // prologue: rows t0 .. t0+23 in flight
    #pragma unroll
    for (int k = 0; k < 24; ++k) LOADROW(k, k);

    float m_run = -FLT_MAX, s_run = 0.f;
    float4 acc = fz;
    float sc[8];

    #pragma unroll
    for (int g = 0; g < 4; ++g) {          // groups A..D, tb = 8g (constants)
        const int tb = g * 8;
        #pragma unroll
        for (int j = 0; j < 8; ++j) {
            float s = DOT4(S[SLOT(tb + j)],     w[0])
                    + DOT4(S[SLOT(tb + j + 1)], w[1])
                    + DOT4(S[SLOT(tb + j + 2)], w[2])
                    + DOT4(S[SLOT(tb + j + 3)], w[3])
                    + DOT4(S[SLOT(tb + j + 4)], w[4]);
            s = wave_sum(s) + bv;
            const int t = t0 + tb + j;
            if (lane == 0) sb[t] = s;
            sc[j] = fminf(s, (t < L) ? MASK_MAG : -MASK_MAG);
        }
        {
            float gm = fmaxf(fmaxf(fmaxf(sc[0], sc[1]), fmaxf(sc[2], sc[3])),
                             fmaxf(fmaxf(sc[4], sc[5]), fmaxf(sc[6], sc[7])));
            const float m_new = fmaxf(m_run, gm);
            const float corr = expf(m_run - m_new);
            float psum = 0.f; float4 ga = fz;
            #pragma unroll
            for (int j = 0; j < 8; ++j) {
                const float p = expf(sc[j] - m_new);
                psum += p;
                const float4 r = S[SLOT(tb + j)];
                ga.x += p * r.x; ga.y += p * r.y;
                ga.z += p * r.z; ga.w += p * r.w;
            }
            s_run = s_run * corr + psum;
            acc.x = acc.x * corr + ga.x; acc.y = acc.y * corr + ga.y;
            acc.z = acc.z * corr + ga.z; acc.w = acc.w * corr + ga.w;
            m_run = m_new;
        }
        if (g == 0) {
            #pragma unroll
            for (int k = 0; k < 8; ++k) LOADROW(SLOT(24 + k), 24 + k);
        } else if (g == 1) {
            #pragma unroll
            for (int k = 0; k < 4; ++k) LOADROW(SLOT(32 + k), 32 + k);
        }
    }
#undef DOT4
#undef LOADROW
#undef SLOT

    const int pw = b * npw + widx;
    *reinterpret_cast<float4*>(pacc + (size_t)pw * F + lane4) = acc;
    if (lane == 0) { pm[pw] = m_run; ps[pw] = s_run; }
}

// ---------------------------------------------------------------------------
// K2: finalize. Grid (B, 9). (identical to R7)
// ---------------------------------------------------------------------------
__global__ __launch_bounds__(256) void finalize_kernel(
    const float* __restrict__ scores, const float* __restrict__ pacc,
    const float* __restrict__ pm, const float* __restrict__ ps,
    const int* __restrict__ seq, float* __restrict__ out_res,
    float* __restrict__ out_w, int T, int npb) {
    const int b = blockIdx.x;
    const int part = blockIdx.y;
    const int tid = threadIdx.x;
    __shared__ float MS[2];
    __shared__ float scale[64];   // npb == 64

    if (tid < 64) {
        const float m = pm[b * npb + tid];
        const float s = ps[b * npb + tid];
        float M = m;
        #pragma unroll
        for (int off = 32; off >= 1; off >>= 1) M = fmaxf(M, __shfl_xor(M, off, 64));
        const float e = expf(m - M);
        float se = e * s;
        #pragma unroll
        for (int off = 32; off >= 1; off >>= 1) se += __shfl_xor(se, off, 64);
        scale[tid] = e;
        if (tid == 0) { MS[0] = M; MS[1] = 1.0f / se; }
    }
    __syncthreads();
    const float M = MS[0], invS = MS[1];

    if (part == 0) {
        float o = 0.f;
        for (int i = 0; i < npb; ++i)
            o += scale[i] * pacc[((size_t)(b * npb + i)) * F + tid];
        out_res[(size_t)b * F + tid] = o * invS;
    } else {
        const int L = seq[b];
        const int chunk = T / 8;
        const int tbase = (part - 1) * chunk;
        for (int t = tbase + tid; t < tbase + chunk; t += 256) {
            const float raw = scores[(size_t)b * T + t];
            const float msk = fminf(raw, (t < L) ? MASK_MAG : -MASK_MAG);
            out_w[(size_t)b * T + t] = expf(msk - M) * invS;
        }
    }
}

extern "C" void kernel_launch(void* const* d_in, const int* in_sizes, int n_in,
                              void* d_out, int out_size, void* d_ws, size_t ws_size,
                              hipStream_t stream) {
    const float* data = (const float*)d_in[0];
    const int*   seq  = (const int*)d_in[1];
    const float* W    = (const float*)d_in[2];
    const float* bias = (const float*)d_in[3];

    const int B  = in_sizes[1];                 // 32
    const int Fr = in_sizes[2] / SCOPE;         // 256 (== F)
    const int T  = in_sizes[0] / (B * Fr);      // 2048
    (void)Fr;
    const int npw = T / TW;                     // 64 wave-partials per batch

    float* out_res = (float*)d_out;                      // [B, F]
    float* out_w   = (float*)d_out + (size_t)B * F;      // [B, T]

    // real buffers
    float* scores = (float*)d_ws;                        // B*T
    float* pacc   = scores + (size_t)B * T;              // B*npw*F
    float* pm     = pacc + (size_t)B * npw * F;          // B*npw
    float* ps     = pm + (size_t)B * npw;                // B*npw
    // dummy buffers for the diagnostic clones (separate ws region)
    float* scores2 = ps + (size_t)B * npw;
    float* pacc2   = scores2 + (size_t)B * T;
    float* pm2     = pacc2 + (size_t)B * npw * F;
    float* ps2     = pm2 + (size_t)B * npw;

    dim3 g1(T / (WAVES * TW), B);                        // (16, 32)
    // real K1
    fused_kernel<<<g1, 256, 0, stream>>>(data, W, bias, seq, scores, pacc, pm, ps, T);
    // DIAGNOSTIC: two clones of K1 into dummy buffers. dur - 33.5 = 2*t(K1).
    fused_kernel<<<g1, 256, 0, stream>>>(data, W, bias, seq, scores2, pacc2, pm2, ps2, T);
    fused_kernel<<<g1, 256, 0, stream>>>(data, W, bias, seq, scores2, pacc2, pm2, ps2, T);

    dim3 g2(B, 9);
    finalize_kernel<<<g2, 256, 0, stream>>>(scores, pacc, pm, ps, seq, out_res, out_w, T, npw);
}

// Round 10
// 33.734 us; speedup vs baseline: 2.4027x; 2.4027x over previous
//
#include <hip/hip_runtime.h>
#include <cfloat>

#define SCOPE 5
#define MASK_MAG 9999.0f
constexpr int F = 256;     // hiddenNoduleNumbers
constexpr int TW = 32;     // t's per wave
constexpr int WAVES = 4;   // waves per block

// DPP partial reduce (within 16 lanes) + 2 cross-group shuffles -> 64-lane sum.
template <int CTRL>
__device__ __forceinline__ float dppadd(float x) {
    int v = __builtin_amdgcn_update_dpp(0, __float_as_int(x), CTRL, 0xF, 0xF, true);
    return x + __int_as_float(v);
}
__device__ __forceinline__ float wave_sum(float s) {
    s = dppadd<0xB1>(s);   // + lane^1
    s = dppadd<0x4E>(s);   // + lane^2
    s = dppadd<0x141>(s);  // + lane^4 (row_half_mirror)
    s = dppadd<0x140>(s);  // + lane^8 (row_mirror)
    s += __shfl_xor(s, 16, 64);
    s += __shfl_xor(s, 32, 64);
    return s;
}

// ---------------------------------------------------------------------------
// K1: fused sliding-window scores + online-softmax weighted accumulation.
// Ring-20 of rows (float4/lane) with ALL slot indices literal constants
// (rule #20: any runtime-indexed register array goes to scratch and
// serializes every access). Four group bodies written out explicitly.
// Refills are issued one full group (~8 t of compute) before first use.
// ---------------------------------------------------------------------------
__global__ __launch_bounds__(256) void fused_kernel(
    const float* __restrict__ data, const float* __restrict__ W,
    const float* __restrict__ bias, const int* __restrict__ seq,
    float* __restrict__ scores, float* __restrict__ pacc,
    float* __restrict__ pm, float* __restrict__ ps, int T) {
    const int b = blockIdx.y;
    const int tid = threadIdx.x;
    const int lane = tid & 63;
    const int wid = tid >> 6;
    const int lane4 = lane * 4;
    const int widx = blockIdx.x * WAVES + wid;
    const int t0 = widx * TW;
    const int npw = T / TW;
    const float* __restrict__ dBase = data + (size_t)b * T * F;
    float* __restrict__ sbase = scores + (size_t)b * T;
    const float bv = bias[0];
    const int L = seq[b];

    float4 w[SCOPE];
    #pragma unroll
    for (int v = 0; v < SCOPE; ++v)
        w[v] = *(const float4*)(W + v * F + lane4);

    const float4 fz = make_float4(0.f, 0.f, 0.f, 0.f);
    float4 S[20];
    float scr[8];
    float m_run = -FLT_MAX, s_run = 0.f;
    float4 acc = fz;

#define RF(slot, off) do { \
    const int uu = t0 + (off); \
    S[slot] = (uu < T) ? *(const float4*)(dBase + (size_t)uu * F + lane4) : fz; \
    } while (0)
#define DOT4(a, b) ((a).x*(b).x + (a).y*(b).y + (a).z*(b).z + (a).w*(b).w)
// score for t = t0+TJ from ring slots A_..E_ (all literals), stash in scr[K_]
#define STEP(TJ, A_, B_, C_, D_, E_, K_) { \
    float s = DOT4(S[A_], w[0]) + DOT4(S[B_], w[1]) + DOT4(S[C_], w[2]) \
            + DOT4(S[D_], w[3]) + DOT4(S[E_], w[4]); \
    s = wave_sum(s) + bv; \
    const int t = t0 + (TJ); \
    if (lane == 0) sbase[t] = s; \
    scr[K_] = fminf(s, (t < L) ? MASK_MAG : -MASK_MAG); }
// online-softmax update consuming rows in slots S0_..S7_ (literals)
#define ACC8(S0_,S1_,S2_,S3_,S4_,S5_,S6_,S7_) { \
    float gm = fmaxf(fmaxf(fmaxf(scr[0], scr[1]), fmaxf(scr[2], scr[3])), \
                     fmaxf(fmaxf(scr[4], scr[5]), fmaxf(scr[6], scr[7]))); \
    const float m_new = fmaxf(m_run, gm); \
    const float corr = expf(m_run - m_new); \
    const float p0 = expf(scr[0] - m_new), p1 = expf(scr[1] - m_new); \
    const float p2 = expf(scr[2] - m_new), p3 = expf(scr[3] - m_new); \
    const float p4 = expf(scr[4] - m_new), p5 = expf(scr[5] - m_new); \
    const float p6 = expf(scr[6] - m_new), p7 = expf(scr[7] - m_new); \
    s_run = s_run * corr + (((p0+p1)+(p2+p3)) + ((p4+p5)+(p6+p7))); \
    acc.x = acc.x * corr + p0*S[S0_].x + p1*S[S1_].x + p2*S[S2_].x + p3*S[S3_].x \
                         + p4*S[S4_].x + p5*S[S5_].x + p6*S[S6_].x + p7*S[S7_].x; \
    acc.y = acc.y * corr + p0*S[S0_].y + p1*S[S1_].y + p2*S[S2_].y + p3*S[S3_].y \
                         + p4*S[S4_].y + p5*S[S5_].y + p6*S[S6_].y + p7*S[S7_].y; \
    acc.z = acc.z * corr + p0*S[S0_].z + p1*S[S1_].z + p2*S[S2_].z + p3*S[S3_].z \
                         + p4*S[S4_].z + p5*S[S5_].z + p6*S[S6_].z + p7*S[S7_].z; \
    acc.w = acc.w * corr + p0*S[S0_].w + p1*S[S1_].w + p2*S[S2_].w + p3*S[S3_].w \
                         + p4*S[S4_].w + p5*S[S5_].w + p6*S[S6_].w + p7*S[S7_].w; \
    m_run = m_new; }

    // prologue: slots 0..19 <- rows t0..t0+19
    RF(0,0); RF(1,1); RF(2,2); RF(3,3); RF(4,4); RF(5,5); RF(6,6); RF(7,7);
    RF(8,8); RF(9,9); RF(10,10); RF(11,11); RF(12,12); RF(13,13); RF(14,14);
    RF(15,15); RF(16,16); RF(17,17); RF(18,18); RF(19,19);

    // ---- group A: t0+0..7, rows 0..11 in slots 0..11 ----
    STEP(0, 0,1,2,3,4, 0)  STEP(1, 1,2,3,4,5, 1)  STEP(2, 2,3,4,5,6, 2)
    STEP(3, 3,4,5,6,7, 3)  STEP(4, 4,5,6,7,8, 4)  STEP(5, 5,6,7,8,9, 5)
    STEP(6, 6,7,8,9,10, 6) STEP(7, 7,8,9,10,11, 7)
    ACC8(0,1,2,3,4,5,6,7)
    // refill slots 0..7 <- rows 20..27 (first used in group C)
    RF(0,20); RF(1,21); RF(2,22); RF(3,23); RF(4,24); RF(5,25); RF(6,26); RF(7,27);

    // ---- group B: t0+8..15, rows 8..19 in slots 8..19 ----
    STEP(8,  8,9,10,11,12, 0)  STEP(9,  9,10,11,12,13, 1)
    STEP(10, 10,11,12,13,14, 2) STEP(11, 11,12,13,14,15, 3)
    STEP(12, 12,13,14,15,16, 4) STEP(13, 13,14,15,16,17, 5)
    STEP(14, 14,15,16,17,18, 6) STEP(15, 15,16,17,18,19, 7)
    ACC8(8,9,10,11,12,13,14,15)
    // refill slots 8..15 <- rows 28..35 (first used in group D)
    RF(8,28); RF(9,29); RF(10,30); RF(11,31); RF(12,32); RF(13,33); RF(14,34); RF(15,35);

    // ---- group C: t0+16..23, rows 16..27 in slots 16..19,0..7 ----
    STEP(16, 16,17,18,19,0, 0) STEP(17, 17,18,19,0,1, 1)
    STEP(18, 18,19,0,1,2, 2)   STEP(19, 19,0,1,2,3, 3)
    STEP(20, 0,1,2,3,4, 4)     STEP(21, 1,2,3,4,5, 5)
    STEP(22, 2,3,4,5,6, 6)     STEP(23, 3,4,5,6,7, 7)
    ACC8(16,17,18,19,0,1,2,3)

    // ---- group D: t0+24..31, rows 24..35 in slots 4..15 ----
    STEP(24, 4,5,6,7,8, 0)     STEP(25, 5,6,7,8,9, 1)
    STEP(26, 6,7,8,9,10, 2)    STEP(27, 7,8,9,10,11, 3)
    STEP(28, 8,9,10,11,12, 4)  STEP(29, 9,10,11,12,13, 5)
    STEP(30, 10,11,12,13,14, 6) STEP(31, 11,12,13,14,15, 7)
    ACC8(4,5,6,7,8,9,10,11)

#undef ACC8
#undef STEP
#undef DOT4
#undef RF

    // per-wave partials
    const int pw = b * npw + widx;
    *reinterpret_cast<float4*>(pacc + (size_t)pw * F + lane4) = acc;
    if (lane == 0) { pm[pw] = m_run; ps[pw] = s_run; }
}

// ---------------------------------------------------------------------------
// K2: finalize. Grid (B, 9). Each block recomputes global (M, invS) from the
// npb=64 wave partials. y==0: reduce pacc -> attentionResult. y=1..8: weights.
// ---------------------------------------------------------------------------
__global__ __launch_bounds__(256) void finalize_kernel(
    const float* __restrict__ scores, const float* __restrict__ pacc,
    const float* __restrict__ pm, const float* __restrict__ ps,
    const int* __restrict__ seq, float* __restrict__ out_res,
    float* __restrict__ out_w, int T, int npb) {
    const int b = blockIdx.x;
    const int part = blockIdx.y;
    const int tid = threadIdx.x;
    __shared__ float MS[2];
    __shared__ float scale[64];   // npb == 64

    if (tid < 64) {
        const float m = pm[b * npb + tid];
        const float s = ps[b * npb + tid];
        float M = m;
        #pragma unroll
        for (int off = 32; off >= 1; off >>= 1) M = fmaxf(M, __shfl_xor(M, off, 64));
        const float e = expf(m - M);
        float se = e * s;
        #pragma unroll
        for (int off = 32; off >= 1; off >>= 1) se += __shfl_xor(se, off, 64);
        scale[tid] = e;
        if (tid == 0) { MS[0] = M; MS[1] = 1.0f / se; }
    }
    __syncthreads();
    const float M = MS[0], invS = MS[1];

    if (part == 0) {
        float o = 0.f;
        for (int i = 0; i < npb; ++i)
            o += scale[i] * pacc[((size_t)(b * npb + i)) * F + tid];
        out_res[(size_t)b * F + tid] = o * invS;
    } else {
        const int L = seq[b];
        const int chunk = T / 8;
        const int tbase = (part - 1) * chunk;
        for (int t = tbase + tid; t < tbase + chunk; t += 256) {
            const float raw = scores[(size_t)b * T + t];
            const float msk = fminf(raw, (t < L) ? MASK_MAG : -MASK_MAG);
            out_w[(size_t)b * T + t] = expf(msk - M) * invS;
        }
    }
}

extern "C" void kernel_launch(void* const* d_in, const int* in_sizes, int n_in,
                              void* d_out, int out_size, void* d_ws, size_t ws_size,
                              hipStream_t stream) {
    const float* data = (const float*)d_in[0];
    const int*   seq  = (const int*)d_in[1];
    const float* W    = (const float*)d_in[2];
    const float* bias = (const float*)d_in[3];

    const int B  = in_sizes[1];                 // 32
    const int Fr = in_sizes[2] / SCOPE;         // 256 (== F)
    const int T  = in_sizes[0] / (B * Fr);      // 2048
    (void)Fr;
    const int npw = T / TW;                     // 64 wave-partials per batch

    float* out_res = (float*)d_out;                      // [B, F]
    float* out_w   = (float*)d_out + (size_t)B * F;      // [B, T]

    float* scores = (float*)d_ws;                        // B*T
    float* pacc   = scores + (size_t)B * T;              // B*npw*F
    float* pm     = pacc + (size_t)B * npw * F;          // B*npw
    float* ps     = pm + (size_t)B * npw;                // B*npw

    dim3 g1(T / (WAVES * TW), B);                        // (16, 32)
    fused_kernel<<<g1, 256, 0, stream>>>(data, W, bias, seq, scores, pacc, pm, ps, T);
    dim3 g2(B, 9);
    finalize_kernel<<<g2, 256, 0, stream>>>(scores, pacc, pm, ps, seq, out_res, out_w, T, npw);
}